// Round 1
// baseline (317.347 us; speedup 1.0000x reference)
//
#include <hip/hip_runtime.h>
#include <stdint.h>
#include <stddef.h>

#define DEVINL __device__ __forceinline__

typedef __attribute__((ext_vector_type(8))) __bf16 bf16x8;
typedef __attribute__((ext_vector_type(4))) float f32x4;
typedef __attribute__((ext_vector_type(4))) unsigned short us4;
typedef __attribute__((ext_vector_type(8))) unsigned short us8;

typedef __attribute__((address_space(1))) unsigned int as1_uint;
typedef __attribute__((address_space(3))) unsigned int as3_uint;

constexpr int SEQ    = 2048;
constexpr int DMODEL = 1024;
constexpr int MTOT   = 4096;    // B*L
constexpr int NQKV   = 3072;
constexpr int DKH    = 64;

// workspace layout (bytes)
constexpr size_t OFF_XBF  = 0;                                      // 8 MiB
constexpr size_t OFF_WQKV = OFF_XBF  + (size_t)MTOT * DMODEL * 2;   // 6 MiB
constexpr size_t OFF_WOUT = OFF_WQKV + (size_t)NQKV * DMODEL * 2;   // 2 MiB
constexpr size_t OFF_Q    = OFF_WOUT + (size_t)DMODEL * DMODEL * 2; // 8 MiB
constexpr size_t OFF_K    = OFF_Q    + (size_t)MTOT * DMODEL * 2;   // 8 MiB
constexpr size_t OFF_VT   = OFF_K    + (size_t)MTOT * DMODEL * 2;   // 8 MiB
constexpr size_t OFF_O    = OFF_VT   + (size_t)MTOT * DMODEL * 2;   // 8 MiB
constexpr size_t OFF_ROPE = OFF_O    + (size_t)MTOT * DMODEL * 2;   // 1 MiB

DEVINL unsigned short f2bf(float f) {
  unsigned int u = __float_as_uint(f);
  u += 0x7fffu + ((u >> 16) & 1u);
  return (unsigned short)(u >> 16);
}

DEVINL void gld_lds16(const unsigned short* g, unsigned short* s) {
  __builtin_amdgcn_global_load_lds((as1_uint*)g, (as3_uint*)s, 16, 0, 0);
}

// ---------------- prep: fp32->bf16 converts + rope table ----------------
__global__ __launch_bounds__(256) void prep_kernel(
    const float* __restrict__ X, const float* __restrict__ Wqkv,
    const float* __restrict__ Wout, const int* __restrict__ pos,
    unsigned short* __restrict__ xbf, unsigned short* __restrict__ wqkvbf,
    unsigned short* __restrict__ woutbf, float2* __restrict__ rope) {
  const int t = blockIdx.x * 256 + threadIdx.x;
  if (t < MTOT * 32) {  // rope table: (m, pair)
    const int m = t >> 5, ip = t & 31;
    const float freq = powf(10000.0f, -(float)(2 * ip) / 64.0f);
    const float ang = (float)pos[m] * freq;
    float sv, cv;
    sincosf(ang, &sv, &cv);
    rope[t] = make_float2(cv, sv);
  }
  const int NX = MTOT * DMODEL, NW1 = NQKV * DMODEL, NW2 = DMODEL * DMODEL;
  const int e = t * 4;
  const float* src;
  unsigned short* dst;
  if (e < NX) { src = X + e; dst = xbf + e; }
  else if (e < NX + NW1) { src = Wqkv + (e - NX); dst = wqkvbf + (e - NX); }
  else if (e < NX + NW1 + NW2) { src = Wout + (e - NX - NW1); dst = woutbf + (e - NX - NW1); }
  else return;
  const float4 v = *(const float4*)src;
  us4 o = { f2bf(v.x), f2bf(v.y), f2bf(v.z), f2bf(v.w) };
  *(us4*)dst = o;
}

// ---------------- GEMM: C[m][n] = sum_k A[m][k]*B[n][k], 128x128 tile ----------------
// MODE 0: A=Xbf, B=Wqkv -> RoPE epilogue, scatter Q/K row-major, V transposed per head.
// MODE 1: A=Obf,  B=Wout -> fp32 store to d_out.
template <int MODE>
__global__ __launch_bounds__(256) void gemm_kernel(
    const unsigned short* __restrict__ A, const unsigned short* __restrict__ Bw,
    unsigned short* __restrict__ q_out, unsigned short* __restrict__ k_out,
    unsigned short* __restrict__ vt_out, const float2* __restrict__ rope,
    float* __restrict__ f_out) {
  constexpr int K = DMODEL;  // 1024
  __shared__ __align__(16) unsigned short As[128 * 32];
  __shared__ __align__(16) unsigned short Bs[128 * 32];
  const int tid = threadIdx.x;
  const int l = tid & 63, w = tid >> 6;
  const int g = l >> 4, l15 = l & 15;
  const int m0 = blockIdx.y * 128, n0 = blockIdx.x * 128;
  const int wm = w >> 1, wn = w & 1;

  // staging: per wave 1KiB per instr; lane chunk = base + l*16 bytes in LDS
  const unsigned short* ag = A  + (size_t)(m0 + w * 16 + (l >> 2)) * K + (l & 3) * 8;
  const unsigned short* bg = Bw + (size_t)(n0 + w * 16 + (l >> 2)) * K + (l & 3) * 8;
  unsigned short* as0 = As + w * 512;
  unsigned short* bs0 = Bs + w * 512;

  const f32x4 zf = {0.f, 0.f, 0.f, 0.f};
  f32x4 acc[4][4];
#pragma unroll
  for (int i = 0; i < 4; ++i)
#pragma unroll
    for (int j = 0; j < 4; ++j) acc[i][j] = zf;

  for (int kt = 0; kt < K / 32; ++kt) {
    const unsigned short* a0 = ag + kt * 32;
    const unsigned short* b0 = bg + kt * 32;
    gld_lds16(a0, as0);
    gld_lds16(a0 + (size_t)64 * K, as0 + 2048);
    gld_lds16(b0, bs0);
    gld_lds16(b0 + (size_t)64 * K, bs0 + 2048);
    __syncthreads();
    bf16x8 af[4], bf[4];
#pragma unroll
    for (int i = 0; i < 4; ++i)
      af[i] = *(const bf16x8*)(As + (wm * 64 + i * 16 + l15) * 32 + g * 8);
#pragma unroll
    for (int j = 0; j < 4; ++j)
      bf[j] = *(const bf16x8*)(Bs + (wn * 64 + j * 16 + l15) * 32 + g * 8);
#pragma unroll
    for (int i = 0; i < 4; ++i)
#pragma unroll
      for (int j = 0; j < 4; ++j)
        acc[i][j] = __builtin_amdgcn_mfma_f32_16x16x32_bf16(af[i], bf[j], acc[i][j], 0, 0, 0);
    __syncthreads();
  }

  if constexpr (MODE == 0) {
    const int region = n0 >> 10;  // 0=Q 1=K 2=V (128 | 1024 region boundaries)
    if (region <= 1) {
      unsigned short* outb = (region == 0) ? q_out : k_out;
#pragma unroll
      for (int i = 0; i < 4; ++i) {
        const int mb = m0 + wm * 64 + i * 16 + g * 4;
#pragma unroll
        for (int j = 0; j < 4; ++j) {
          const int n = n0 + wn * 64 + j * 16 + l15;
          const int ncol = n & 1023;
          const int ip = (n & 63) >> 1;
          const float sgn = (n & 1) ? 1.f : -1.f;
#pragma unroll
          for (int r = 0; r < 4; ++r) {
            const int m = mb + r;
            const float v = acc[i][j][r];
            const float p = __shfl_xor(v, 1);  // partner column n^1
            const float2 cs = rope[m * 32 + ip];
            const float o = v * cs.x + sgn * p * cs.y;  // even: v*c - p*s ; odd: v*c + p*s
            outb[(size_t)m * DMODEL + ncol] = f2bf(o);
          }
        }
      }
    } else {  // V -> transposed per head: Vt[(b*1024 + h*64 + d)][l]
#pragma unroll
      for (int i = 0; i < 4; ++i) {
        const int mb = m0 + wm * 64 + i * 16 + g * 4;
        const int b = mb >> 11;
        const int lseq = mb & 2047;
#pragma unroll
        for (int j = 0; j < 4; ++j) {
          const int n = n0 + wn * 64 + j * 16 + l15;
          const int hd = n - 2048;
          us4 o = { f2bf(acc[i][j][0]), f2bf(acc[i][j][1]), f2bf(acc[i][j][2]), f2bf(acc[i][j][3]) };
          *(us4*)(vt_out + (size_t)(b * DMODEL + hd) * SEQ + lseq) = o;
        }
      }
    }
  } else {
#pragma unroll
    for (int i = 0; i < 4; ++i) {
      const int mb = m0 + wm * 64 + i * 16 + g * 4;
#pragma unroll
      for (int j = 0; j < 4; ++j) {
        const int n = n0 + wn * 64 + j * 16 + l15;
#pragma unroll
        for (int r = 0; r < 4; ++r) f_out[(size_t)(mb + r) * DMODEL + n] = acc[i][j][r];
      }
    }
  }
}

// ---------------- causal flash attention, swapped-QK^T, O^T in-register ----------------
__global__ __launch_bounds__(256) void attn_kernel(
    const unsigned short* __restrict__ Qb, const unsigned short* __restrict__ Kb,
    const unsigned short* __restrict__ Vt, unsigned short* __restrict__ Ob) {
  __shared__ __align__(16) unsigned short Olds[4][16][72];
  const int tid = threadIdx.x;
  const int l = tid & 63, w = tid >> 6;
  const int g = l >> 4, q15 = l & 15;
  const int bh = blockIdx.y;
  const int b = bh >> 4, h = bh & 15;
  const int qw = blockIdx.x * 64 + w * 16;  // wave's q-row base

  const unsigned short* qp = Qb + (size_t)(b * SEQ + qw + q15) * DMODEL + h * DKH + g * 8;
  const bf16x8 qf0 = *(const bf16x8*)qp;
  const bf16x8 qf1 = *(const bf16x8*)(qp + 32);

  const unsigned short* kb = Kb + (size_t)(b * SEQ) * DMODEL + h * DKH + g * 8;
  const unsigned short* vb = Vt + (size_t)(b * DMODEL + h * DKH + q15) * SEQ + g * 8;

  const f32x4 zf = {0.f, 0.f, 0.f, 0.f};
  float mrun = -1e30f, lrun = 0.f;
  f32x4 ot[4];
#pragma unroll
  for (int d = 0; d < 4; ++d) ot[d] = zf;

  const int nkt = (qw >> 6) + 1;
  for (int kt = 0; kt < nkt; ++kt) {
    const int k0 = kt * 64;
    const bool domask = (kt == nkt - 1);
    float pv[4][4];
    float mt = -1e30f;
#pragma unroll
    for (int blk = 0; blk < 4; ++blk) {
      const unsigned short* kp = kb + (size_t)(k0 + blk * 16 + q15) * DMODEL;
      f32x4 c = zf;
      c = __builtin_amdgcn_mfma_f32_16x16x32_bf16(*(const bf16x8*)kp, qf0, c, 0, 0, 0);
      c = __builtin_amdgcn_mfma_f32_16x16x32_bf16(*(const bf16x8*)(kp + 32), qf1, c, 0, 0, 0);
#pragma unroll
      for (int r = 0; r < 4; ++r) {
        float s = c[r] * 0.125f;  // 1/sqrt(64)
        if (domask && (k0 + blk * 16 + g * 4 + r > qw + q15)) s = -1e30f;
        pv[blk][r] = s;
        mt = fmaxf(mt, s);
      }
    }
    mt = fmaxf(mt, __shfl_xor(mt, 16));
    mt = fmaxf(mt, __shfl_xor(mt, 32));
    const float mnew = fmaxf(mrun, mt);
    const float alpha = __expf(mrun - mnew);
    float rs = 0.f;
#pragma unroll
    for (int blk = 0; blk < 4; ++blk)
#pragma unroll
      for (int r = 0; r < 4; ++r) {
        const float p = __expf(pv[blk][r] - mnew);
        pv[blk][r] = p;
        rs += p;
      }
    rs += __shfl_xor(rs, 16);
    rs += __shfl_xor(rs, 32);
    lrun = lrun * alpha + rs;
    mrun = mnew;
#pragma unroll
    for (int d = 0; d < 4; ++d) ot[d] *= alpha;

    // pack P (bf16 pairs along k) and redistribute to PV B-fragment layout
    unsigned int plo[4], phi[4];
#pragma unroll
    for (int blk = 0; blk < 4; ++blk) {
      plo[blk] = (unsigned int)f2bf(pv[blk][0]) | ((unsigned int)f2bf(pv[blk][1]) << 16);
      phi[blk] = (unsigned int)f2bf(pv[blk][2]) | ((unsigned int)f2bf(pv[blk][3]) << 16);
    }
    const int srcA = (g & 1) * 32 + q15;
    const int srcB = srcA + 16;
    const bool sel = (g >> 1) != 0;
    bf16x8 pf[2];
#pragma unroll
    for (int m = 0; m < 2; ++m) {
      const unsigned int lo0A = (unsigned int)__shfl((int)plo[2 * m], srcA);
      const unsigned int lo1A = (unsigned int)__shfl((int)plo[2 * m + 1], srcA);
      const unsigned int hi0A = (unsigned int)__shfl((int)phi[2 * m], srcA);
      const unsigned int hi1A = (unsigned int)__shfl((int)phi[2 * m + 1], srcA);
      const unsigned int lo0B = (unsigned int)__shfl((int)plo[2 * m], srcB);
      const unsigned int lo1B = (unsigned int)__shfl((int)plo[2 * m + 1], srcB);
      const unsigned int hi0B = (unsigned int)__shfl((int)phi[2 * m], srcB);
      const unsigned int hi1B = (unsigned int)__shfl((int)phi[2 * m + 1], srcB);
      union { unsigned int u[4]; bf16x8 v; } pk;
      pk.u[0] = sel ? lo1A : lo0A;
      pk.u[1] = sel ? hi1A : hi0A;
      pk.u[2] = sel ? lo1B : lo0B;
      pk.u[3] = sel ? hi1B : hi0B;
      pf[m] = pk.v;
    }
    // O^T += Vt * P^T
#pragma unroll
    for (int d = 0; d < 4; ++d) {
      const unsigned short* vp = vb + (size_t)(d * 16) * SEQ + k0;
      ot[d] = __builtin_amdgcn_mfma_f32_16x16x32_bf16(*(const bf16x8*)vp, pf[0], ot[d], 0, 0, 0);
      ot[d] = __builtin_amdgcn_mfma_f32_16x16x32_bf16(*(const bf16x8*)(vp + 32), pf[1], ot[d], 0, 0, 0);
    }
  }

  // epilogue: O^T -> O via LDS transpose, /lrun, bf16 store
  const float inv = 1.0f / lrun;
#pragma unroll
  for (int d = 0; d < 4; ++d) {
    us4 o = { f2bf(ot[d][0] * inv), f2bf(ot[d][1] * inv), f2bf(ot[d][2] * inv), f2bf(ot[d][3] * inv) };
    *(us4*)&Olds[w][q15][d * 16 + g * 4] = o;
  }
  __syncthreads();
  const int r = l >> 2;
  const int c = (l & 3) * 16;
  const us8 v0 = *(const us8*)&Olds[w][r][c];
  const us8 v1 = *(const us8*)&Olds[w][r][c + 8];
  unsigned short* ob = Ob + (size_t)(b * SEQ + blockIdx.x * 64 + w * 16 + r) * DMODEL + h * DKH + c;
  *(us8*)ob = v0;
  *(us8*)(ob + 8) = v1;
}

// ---------------- launch ----------------
extern "C" void kernel_launch(void* const* d_in, const int* in_sizes, int n_in,
                              void* d_out, int out_size, void* d_ws, size_t ws_size,
                              hipStream_t stream) {
  const float* X = (const float*)d_in[0];
  const int* pos = (const int*)d_in[1];
  const float* Wqkv = (const float*)d_in[2];
  const float* Wout = (const float*)d_in[3];
  char* ws = (char*)d_ws;
  unsigned short* xbf    = (unsigned short*)(ws + OFF_XBF);
  unsigned short* wqkvbf = (unsigned short*)(ws + OFF_WQKV);
  unsigned short* woutbf = (unsigned short*)(ws + OFF_WOUT);
  unsigned short* qb     = (unsigned short*)(ws + OFF_Q);
  unsigned short* kbuf   = (unsigned short*)(ws + OFF_K);
  unsigned short* vt     = (unsigned short*)(ws + OFF_VT);
  unsigned short* ob     = (unsigned short*)(ws + OFF_O);
  float2* rope           = (float2*)(ws + OFF_ROPE);

  prep_kernel<<<8192, 256, 0, stream>>>(X, Wqkv, Wout, pos, xbf, wqkvbf, woutbf, rope);
  gemm_kernel<0><<<dim3(NQKV / 128, MTOT / 128), 256, 0, stream>>>(
      xbf, wqkvbf, qb, kbuf, vt, rope, nullptr);
  attn_kernel<<<dim3(SEQ / 64, 32), 256, 0, stream>>>(qb, kbuf, vt, ob);
  gemm_kernel<1><<<dim3(DMODEL / 128, MTOT / 128), 256, 0, stream>>>(
      ob, woutbf, nullptr, nullptr, nullptr, nullptr, (float*)d_out);
}

// Round 2
// 156.588 us; speedup vs baseline: 2.0266x; 2.0266x over previous
//
#include <hip/hip_runtime.h>
#include <stdint.h>
#include <stddef.h>

#define DEVINL __device__ __forceinline__

typedef __attribute__((ext_vector_type(8))) __bf16 bf16x8;
typedef __attribute__((ext_vector_type(4))) float f32x4;
typedef __attribute__((ext_vector_type(4))) unsigned short us4;
typedef __attribute__((ext_vector_type(8))) unsigned short us8;

typedef __attribute__((address_space(1))) unsigned int as1_uint;
typedef __attribute__((address_space(3))) unsigned int as3_uint;

constexpr int SEQ    = 2048;
constexpr int DMODEL = 1024;
constexpr int MTOT   = 4096;    // B*L
constexpr int NQKV   = 3072;
constexpr int DKH    = 64;

// workspace layout (bytes)
constexpr size_t OFF_XBF  = 0;                                      // 8 MiB
constexpr size_t OFF_WQKV = OFF_XBF  + (size_t)MTOT * DMODEL * 2;   // 6 MiB
constexpr size_t OFF_WOUT = OFF_WQKV + (size_t)NQKV * DMODEL * 2;   // 2 MiB
constexpr size_t OFF_Q    = OFF_WOUT + (size_t)DMODEL * DMODEL * 2; // 8 MiB
constexpr size_t OFF_K    = OFF_Q    + (size_t)MTOT * DMODEL * 2;   // 8 MiB
constexpr size_t OFF_VT   = OFF_K    + (size_t)MTOT * DMODEL * 2;   // 8 MiB
constexpr size_t OFF_O    = OFF_VT   + (size_t)MTOT * DMODEL * 2;   // 8 MiB
constexpr size_t OFF_ROPE = OFF_O    + (size_t)MTOT * DMODEL * 2;   // 1 MiB

DEVINL unsigned short f2bf(float f) {
  unsigned int u = __float_as_uint(f);
  u += 0x7fffu + ((u >> 16) & 1u);
  return (unsigned short)(u >> 16);
}

DEVINL void gld_lds16(const unsigned short* g, unsigned short* s) {
  __builtin_amdgcn_global_load_lds((as1_uint*)g, (as3_uint*)s, 16, 0, 0);
}

// ---------------- prep: fp32->bf16 converts + rope table ----------------
__global__ __launch_bounds__(256) void prep_kernel(
    const float* __restrict__ X, const float* __restrict__ Wqkv,
    const float* __restrict__ Wout, const int* __restrict__ pos,
    unsigned short* __restrict__ xbf, unsigned short* __restrict__ wqkvbf,
    unsigned short* __restrict__ woutbf, float2* __restrict__ rope) {
  const int t = blockIdx.x * 256 + threadIdx.x;
  if (t < MTOT * 32) {  // rope table: (m, pair)
    const int m = t >> 5, ip = t & 31;
    const float freq = powf(10000.0f, -(float)(2 * ip) / 64.0f);
    const float ang = (float)pos[m] * freq;
    float sv, cv;
    sincosf(ang, &sv, &cv);
    rope[t] = make_float2(cv, sv);
  }
  const int NX = MTOT * DMODEL, NW1 = NQKV * DMODEL, NW2 = DMODEL * DMODEL;
  const int e = t * 4;
  const float* src;
  unsigned short* dst;
  if (e < NX) { src = X + e; dst = xbf + e; }
  else if (e < NX + NW1) { src = Wqkv + (e - NX); dst = wqkvbf + (e - NX); }
  else if (e < NX + NW1 + NW2) { src = Wout + (e - NX - NW1); dst = woutbf + (e - NX - NW1); }
  else return;
  const float4 v = *(const float4*)src;
  us4 o = { f2bf(v.x), f2bf(v.y), f2bf(v.z), f2bf(v.w) };
  *(us4*)dst = o;
}

// ---------------- GEMM: C[m][n] = sum_k A[m][k]*B[n][k], 128x128 tile ----------------
// MODE 0: A=Xbf, B=Wqkv -> RoPE epilogue, scatter Q/K row-major, V transposed per head.
// MODE 1: A=Obf,  B=Wout -> fp32 store to d_out.
template <int MODE>
__global__ __launch_bounds__(256) void gemm_kernel(
    const unsigned short* __restrict__ A, const unsigned short* __restrict__ Bw,
    unsigned short* __restrict__ q_out, unsigned short* __restrict__ k_out,
    unsigned short* __restrict__ vt_out, const float2* __restrict__ rope,
    float* __restrict__ f_out) {
  constexpr int K = DMODEL;  // 1024
  __shared__ __align__(16) unsigned short As[128 * 32];
  __shared__ __align__(16) unsigned short Bs[128 * 32];
  const int tid = threadIdx.x;
  const int l = tid & 63, w = tid >> 6;
  const int g = l >> 4, l15 = l & 15;
  const int m0 = blockIdx.y * 128, n0 = blockIdx.x * 128;
  const int wm = w >> 1, wn = w & 1;

  // staging: per wave 1KiB per instr; lane chunk = base + l*16 bytes in LDS
  const unsigned short* ag = A  + (size_t)(m0 + w * 16 + (l >> 2)) * K + (l & 3) * 8;
  const unsigned short* bg = Bw + (size_t)(n0 + w * 16 + (l >> 2)) * K + (l & 3) * 8;
  unsigned short* as0 = As + w * 512;
  unsigned short* bs0 = Bs + w * 512;

  const f32x4 zf = {0.f, 0.f, 0.f, 0.f};
  f32x4 acc[4][4];
#pragma unroll
  for (int i = 0; i < 4; ++i)
#pragma unroll
    for (int j = 0; j < 4; ++j) acc[i][j] = zf;

  for (int kt = 0; kt < K / 32; ++kt) {
    const unsigned short* a0 = ag + kt * 32;
    const unsigned short* b0 = bg + kt * 32;
    gld_lds16(a0, as0);
    gld_lds16(a0 + (size_t)64 * K, as0 + 2048);
    gld_lds16(b0, bs0);
    gld_lds16(b0 + (size_t)64 * K, bs0 + 2048);
    __syncthreads();
    bf16x8 af[4], bf[4];
#pragma unroll
    for (int i = 0; i < 4; ++i)
      af[i] = *(const bf16x8*)(As + (wm * 64 + i * 16 + l15) * 32 + g * 8);
#pragma unroll
    for (int j = 0; j < 4; ++j)
      bf[j] = *(const bf16x8*)(Bs + (wn * 64 + j * 16 + l15) * 32 + g * 8);
#pragma unroll
    for (int i = 0; i < 4; ++i)
#pragma unroll
      for (int j = 0; j < 4; ++j)
        acc[i][j] = __builtin_amdgcn_mfma_f32_16x16x32_bf16(af[i], bf[j], acc[i][j], 0, 0, 0);
    __syncthreads();
  }

  if constexpr (MODE == 0) {
    const int region = n0 >> 10;  // 0=Q 1=K 2=V (128 | 1024 region boundaries)
    if (region <= 1) {
      unsigned short* outb = (region == 0) ? q_out : k_out;
#pragma unroll
      for (int i = 0; i < 4; ++i) {
        const int mb = m0 + wm * 64 + i * 16 + g * 4;
#pragma unroll
        for (int j = 0; j < 4; ++j) {
          const int n = n0 + wn * 64 + j * 16 + l15;
          const int ncol = n & 1023;
          const int ip = (n & 63) >> 1;
          const float sgn = (n & 1) ? 1.f : -1.f;
#pragma unroll
          for (int r = 0; r < 4; ++r) {
            const int m = mb + r;
            const float v = acc[i][j][r];
            const float p = __shfl_xor(v, 1);  // partner column n^1
            const float2 cs = rope[m * 32 + ip];
            const float o = v * cs.x + sgn * p * cs.y;  // even: v*c - p*s ; odd: v*c + p*s
            outb[(size_t)m * DMODEL + ncol] = f2bf(o);
          }
        }
      }
    } else {  // V -> transposed per head: Vt[(b*1024 + h*64 + d)][l]
#pragma unroll
      for (int i = 0; i < 4; ++i) {
        const int mb = m0 + wm * 64 + i * 16 + g * 4;
        const int b = mb >> 11;
        const int lseq = mb & 2047;
#pragma unroll
        for (int j = 0; j < 4; ++j) {
          const int n = n0 + wn * 64 + j * 16 + l15;
          const int hd = n - 2048;
          us4 o = { f2bf(acc[i][j][0]), f2bf(acc[i][j][1]), f2bf(acc[i][j][2]), f2bf(acc[i][j][3]) };
          *(us4*)(vt_out + (size_t)(b * DMODEL + hd) * SEQ + lseq) = o;
        }
      }
    }
  } else {
#pragma unroll
    for (int i = 0; i < 4; ++i) {
      const int mb = m0 + wm * 64 + i * 16 + g * 4;
#pragma unroll
      for (int j = 0; j < 4; ++j) {
        const int n = n0 + wn * 64 + j * 16 + l15;
#pragma unroll
        for (int r = 0; r < 4; ++r) f_out[(size_t)(mb + r) * DMODEL + n] = acc[i][j][r];
      }
    }
  }
}

// ---------------- causal flash attention v2 ----------------
// Block = 256 threads (4 waves x 16 q-rows). Block j processes q-tiles (31-j, j)
// sequentially -> uniform 33 k-tile iterations. K/V tiles (64x64 bf16) staged in
// LDS via global_load_lds, double-buffered, XOR-swizzled (byte ^= (row&7)<<4)
// applied on the GLOBAL source address (linear LDS dest) and on the ds_read.
__global__ __launch_bounds__(256) void attn_kernel(
    const unsigned short* __restrict__ Qb, const unsigned short* __restrict__ Kb,
    const unsigned short* __restrict__ Vt, unsigned short* __restrict__ Ob) {
  __shared__ __align__(16) unsigned short kv[2][2][4096];  // [buf][K/V][64*64]
  __shared__ __align__(16) unsigned short Olds[4][16][72];
  const int tid = threadIdx.x;
  const int l = tid & 63, w = tid >> 6;
  const int g = l >> 4, q15 = l & 15;
  const int bh = blockIdx.y;
  const int b = bh >> 4, h = bh & 15;
  const int tA = 31 - blockIdx.x;   // long phase q-tile
  const int tB = blockIdx.x;        // short phase q-tile

  // Q fragments for both phases (16 q-rows per wave)
  const unsigned short* qpA = Qb + (size_t)(b * SEQ + tA * 64 + w * 16 + q15) * DMODEL + h * DKH + g * 8;
  const unsigned short* qpB = Qb + (size_t)(b * SEQ + tB * 64 + w * 16 + q15) * DMODEL + h * DKH + g * 8;
  const bf16x8 qA0 = *(const bf16x8*)qpA, qA1 = *(const bf16x8*)(qpA + 32);
  const bf16x8 qB0 = *(const bf16x8*)qpB, qB1 = *(const bf16x8*)(qpB + 32);

  // staging source (pre-swizzled): linear LDS slot o = tid*16 (+4096) holds
  // tile element (row = o>>7, colbyte = (o&127) ^ ((row&7)<<4))
  const int rS = tid >> 3;                                        // rows 0..31 (+32)
  const int cS = (((tid & 7) * 16) ^ ((rS & 7) << 4)) >> 1;       // element col
  const unsigned short* pKg = Kb + (size_t)(b * SEQ + rS) * DMODEL + h * DKH + cS;
  const unsigned short* pVg = Vt + (size_t)(b * DMODEL + h * DKH + rS) * SEQ + cS;

  // swizzled ds_read offsets (elements), row&7 == q15&7 for all blk/d
  const int srow = (q15 & 7) << 4;
  const int oc0 = (srow ^ (g * 16)) >> 1;
  const int oc1 = (srow ^ (g * 16 + 64)) >> 1;

  const f32x4 zf = {0.f, 0.f, 0.f, 0.f};
  float mrun, lrun;
  f32x4 ot[4];

  auto STAGE = [&](int bb, int k0) {
    unsigned short* lk = &kv[bb][0][0] + w * 512;  // wave-uniform base
    unsigned short* lv = &kv[bb][1][0] + w * 512;
    gld_lds16(pKg + (size_t)k0 * DMODEL, lk);
    gld_lds16(pKg + (size_t)(k0 + 32) * DMODEL, lk + 2048);
    gld_lds16(pVg + k0, lv);
    gld_lds16(pVg + (size_t)32 * SEQ + k0, lv + 2048);
  };

  auto STORE = [&](int qt) {
    const float inv = 1.0f / lrun;
#pragma unroll
    for (int d = 0; d < 4; ++d) {
      us4 o = { f2bf(ot[d][0] * inv), f2bf(ot[d][1] * inv), f2bf(ot[d][2] * inv), f2bf(ot[d][3] * inv) };
      *(us4*)&Olds[w][q15][d * 16 + g * 4] = o;
    }
    __syncthreads();
    const int r = l >> 2;
    const int c = (l & 3) * 16;
    const us8 v0 = *(const us8*)&Olds[w][r][c];
    const us8 v1 = *(const us8*)&Olds[w][r][c + 8];
    unsigned short* ob = Ob + (size_t)(b * SEQ + qt * 64 + w * 16 + r) * DMODEL + h * DKH + c;
    *(us8*)ob = v0;
    *(us8*)(ob + 8) = v1;
  };

  mrun = -1e30f; lrun = 0.f;
#pragma unroll
  for (int d = 0; d < 4; ++d) ot[d] = zf;

  STAGE(0, 0);
  __syncthreads();

  for (int i = 0; i < 33; ++i) {
    const int cur = i & 1;
    const bool phaseA = (i <= tA);
    const int kt = phaseA ? i : (i - tA - 1);
    if (i + 1 < 33) {
      const int kn = (i + 1 <= tA) ? (i + 1) : (i - tA);
      STAGE(cur ^ 1, kn * 64);
    }
    const bf16x8 qf0 = phaseA ? qA0 : qB0;
    const bf16x8 qf1 = phaseA ? qA1 : qB1;
    const bool domask = phaseA ? (kt == tA) : (kt == tB);
    const unsigned short* lkb = &kv[cur][0][0] + q15 * 64;
    const unsigned short* lvb = &kv[cur][1][0] + q15 * 64;

    float sp[4][4];
    float mt = -1e30f;
#pragma unroll
    for (int blk = 0; blk < 4; ++blk) {
      const bf16x8 kf0 = *(const bf16x8*)(lkb + blk * 1024 + oc0);
      const bf16x8 kf1 = *(const bf16x8*)(lkb + blk * 1024 + oc1);
      f32x4 c = zf;
      c = __builtin_amdgcn_mfma_f32_16x16x32_bf16(kf0, qf0, c, 0, 0, 0);
      c = __builtin_amdgcn_mfma_f32_16x16x32_bf16(kf1, qf1, c, 0, 0, 0);
#pragma unroll
      for (int r = 0; r < 4; ++r) {
        float s = c[r] * 0.125f;  // 1/sqrt(64)
        if (domask && (blk * 16 + g * 4 + r > w * 16 + q15)) s = -1e30f;
        sp[blk][r] = s;
        mt = fmaxf(mt, s);
      }
    }
    mt = fmaxf(mt, __shfl_xor(mt, 16));
    mt = fmaxf(mt, __shfl_xor(mt, 32));
    const float mnew = fmaxf(mrun, mt);
    const float alpha = __expf(mrun - mnew);
    float rs = 0.f;
#pragma unroll
    for (int blk = 0; blk < 4; ++blk)
#pragma unroll
      for (int r = 0; r < 4; ++r) {
        const float p = __expf(sp[blk][r] - mnew);
        sp[blk][r] = p;
        rs += p;
      }
    rs += __shfl_xor(rs, 16);
    rs += __shfl_xor(rs, 32);
    lrun = lrun * alpha + rs;
    mrun = mnew;
#pragma unroll
    for (int d = 0; d < 4; ++d) ot[d] *= alpha;

    // pack P (bf16 pairs along k) and redistribute to PV B-fragment layout
    unsigned int plo[4], phi[4];
#pragma unroll
    for (int blk = 0; blk < 4; ++blk) {
      plo[blk] = (unsigned int)f2bf(sp[blk][0]) | ((unsigned int)f2bf(sp[blk][1]) << 16);
      phi[blk] = (unsigned int)f2bf(sp[blk][2]) | ((unsigned int)f2bf(sp[blk][3]) << 16);
    }
    const int srcA = (g & 1) * 32 + q15;
    const int srcB = srcA + 16;
    const bool sel = (g >> 1) != 0;
    bf16x8 pf[2];
#pragma unroll
    for (int m = 0; m < 2; ++m) {
      const unsigned int lo0A = (unsigned int)__shfl((int)plo[2 * m], srcA);
      const unsigned int lo1A = (unsigned int)__shfl((int)plo[2 * m + 1], srcA);
      const unsigned int hi0A = (unsigned int)__shfl((int)phi[2 * m], srcA);
      const unsigned int hi1A = (unsigned int)__shfl((int)phi[2 * m + 1], srcA);
      const unsigned int lo0B = (unsigned int)__shfl((int)plo[2 * m], srcB);
      const unsigned int lo1B = (unsigned int)__shfl((int)plo[2 * m + 1], srcB);
      const unsigned int hi0B = (unsigned int)__shfl((int)phi[2 * m], srcB);
      const unsigned int hi1B = (unsigned int)__shfl((int)phi[2 * m + 1], srcB);
      union { unsigned int u[4]; bf16x8 v; } pk;
      pk.u[0] = sel ? lo1A : lo0A;
      pk.u[1] = sel ? hi1A : hi0A;
      pk.u[2] = sel ? lo1B : lo0B;
      pk.u[3] = sel ? hi1B : hi0B;
      pf[m] = pk.v;
    }
    // O^T += Vt * P^T
    __builtin_amdgcn_s_setprio(1);
#pragma unroll
    for (int d = 0; d < 4; ++d) {
      const bf16x8 vf0 = *(const bf16x8*)(lvb + d * 1024 + oc0);
      const bf16x8 vf1 = *(const bf16x8*)(lvb + d * 1024 + oc1);
      ot[d] = __builtin_amdgcn_mfma_f32_16x16x32_bf16(vf0, pf[0], ot[d], 0, 0, 0);
      ot[d] = __builtin_amdgcn_mfma_f32_16x16x32_bf16(vf1, pf[1], ot[d], 0, 0, 0);
    }
    __builtin_amdgcn_s_setprio(0);

    if (phaseA && kt == tA) {  // phase switch: flush A, reset state
      STORE(tA);
      mrun = -1e30f; lrun = 0.f;
#pragma unroll
      for (int d = 0; d < 4; ++d) ot[d] = zf;
    }
    __syncthreads();
  }
  STORE(tB);
}

// ---------------- launch ----------------
extern "C" void kernel_launch(void* const* d_in, const int* in_sizes, int n_in,
                              void* d_out, int out_size, void* d_ws, size_t ws_size,
                              hipStream_t stream) {
  const float* X = (const float*)d_in[0];
  const int* pos = (const int*)d_in[1];
  const float* Wqkv = (const float*)d_in[2];
  const float* Wout = (const float*)d_in[3];
  char* ws = (char*)d_ws;
  unsigned short* xbf    = (unsigned short*)(ws + OFF_XBF);
  unsigned short* wqkvbf = (unsigned short*)(ws + OFF_WQKV);
  unsigned short* woutbf = (unsigned short*)(ws + OFF_WOUT);
  unsigned short* qb     = (unsigned short*)(ws + OFF_Q);
  unsigned short* kbuf   = (unsigned short*)(ws + OFF_K);
  unsigned short* vt     = (unsigned short*)(ws + OFF_VT);
  unsigned short* ob     = (unsigned short*)(ws + OFF_O);
  float2* rope           = (float2*)(ws + OFF_ROPE);

  prep_kernel<<<8192, 256, 0, stream>>>(X, Wqkv, Wout, pos, xbf, wqkvbf, woutbf, rope);
  gemm_kernel<0><<<dim3(NQKV / 128, MTOT / 128), 256, 0, stream>>>(
      xbf, wqkvbf, qb, kbuf, vt, rope, nullptr);
  attn_kernel<<<dim3(16, 32), 256, 0, stream>>>(qb, kbuf, vt, ob);
  gemm_kernel<1><<<dim3(DMODEL / 128, MTOT / 128), 256, 0, stream>>>(
      ob, woutbf, nullptr, nullptr, nullptr, nullptr, (float*)d_out);
}